// Round 5
// baseline (34128.021 us; speedup 1.0000x reference)
//
#include <hip/hip_runtime.h>
#include <math.h>

#define SEQ   512
#define BATCH 128
#define INP   512
#define HID   1024
#define G4    4096   // 4*HID
#define NOUT  4

// ---------------------------------------------------------------------------
// init: transpose h0,c0 [B][H] -> hT,cT [H][B]
// ---------------------------------------------------------------------------
__global__ void init_state(const float* __restrict__ h0, const float* __restrict__ c0,
                           float* __restrict__ hT, float* __restrict__ cT) {
  int idx = blockIdx.x * blockDim.x + threadIdx.x;  // < HID*BATCH
  int b = idx & (BATCH - 1);
  int j = idx >> 7;
  hT[j * BATCH + b] = h0[b * HID + j];
  cT[j * BATCH + b] = c0[b * HID + j];
}

// ---------------------------------------------------------------------------
// transpose a chunk of inputs: in [nrows][INP] -> xt [INP][nrows]
// ---------------------------------------------------------------------------
__global__ void transpose_in(const float* __restrict__ in, float* __restrict__ xt,
                             int nrows) {
  __shared__ float s[32][33];
  int tx = threadIdx.x & 31, ty = threadIdx.x >> 5;  // ty < 8
  int n0 = blockIdx.x * 32, i0 = blockIdx.y * 32;
#pragma unroll
  for (int r = 0; r < 4; r++) {
    int n = n0 + ty + 8 * r;
    s[ty + 8 * r][tx] = in[(size_t)n * INP + i0 + tx];
  }
  __syncthreads();
#pragma unroll
  for (int r = 0; r < 4; r++) {
    int i = i0 + ty + 8 * r;
    xt[(size_t)i * nrows + n0 + tx] = s[tx][ty + 8 * r];
  }
}

// ---------------------------------------------------------------------------
// gemm_xproj: C[4096][N] = W_ih[4096][512] @ Xt[512][N] + (b_ih + b_hh)
// (proven round-1 kernel, unchanged)
// ---------------------------------------------------------------------------
__global__ __launch_bounds__(256, 3)
void gemm_xproj(const float* __restrict__ A, const float* __restrict__ Bm,
                const float* __restrict__ b_ih, const float* __restrict__ b_hh,
                float* __restrict__ C, int N) {
  __shared__ float As[32][128];
  __shared__ float Bs[32][128];
  int t = threadIdx.x;
  int g0 = blockIdx.x * 128;
  int n0 = blockIdx.y * 128;
  int mg = (t >> 4) * 8, nn = (t & 15) * 8;
  float acc[8][8] = {};
  for (int k0 = 0; k0 < INP; k0 += 32) {
#pragma unroll
    for (int r = 0; r < 4; r++) {
      int idx = t + 256 * r;
      int g = idx >> 3, i4 = idx & 7;
      float4 v = *(const float4*)&A[(size_t)(g0 + g) * INP + k0 + 4 * i4];
      As[4 * i4 + 0][g] = v.x; As[4 * i4 + 1][g] = v.y;
      As[4 * i4 + 2][g] = v.z; As[4 * i4 + 3][g] = v.w;
    }
#pragma unroll
    for (int r = 0; r < 4; r++) {
      int idx = t + 256 * r;
      int kk = idx >> 5, n4 = idx & 31;
      *(float4*)&Bs[kk][4 * n4] = *(const float4*)&Bm[(size_t)(k0 + kk) * N + n0 + 4 * n4];
    }
    __syncthreads();
#pragma unroll 4
    for (int kk = 0; kk < 32; kk++) {
      float4 a0 = *(const float4*)&As[kk][mg];
      float4 a1 = *(const float4*)&As[kk][mg + 4];
      float4 bb0 = *(const float4*)&Bs[kk][nn];
      float4 bb1 = *(const float4*)&Bs[kk][nn + 4];
      float av[8] = {a0.x, a0.y, a0.z, a0.w, a1.x, a1.y, a1.z, a1.w};
      float bv[8] = {bb0.x, bb0.y, bb0.z, bb0.w, bb1.x, bb1.y, bb1.z, bb1.w};
#pragma unroll
      for (int i2 = 0; i2 < 8; i2++)
#pragma unroll
        for (int j2 = 0; j2 < 8; j2++)
          acc[i2][j2] = fmaf(av[i2], bv[j2], acc[i2][j2]);
    }
    __syncthreads();
  }
#pragma unroll
  for (int i2 = 0; i2 < 8; i2++) {
    int g = g0 + mg + i2;
    float bias = b_ih[g] + b_hh[g];
#pragma unroll
    for (int j2 = 0; j2 < 8; j2++) {
      C[(size_t)g * N + n0 + nn + j2] = acc[i2][j2] + bias;
    }
  }
}

// ---------------------------------------------------------------------------
// gemm_step: partial GEMM, NO LDS, no __syncthreads.
// Grid (32 mt, 8 kseg) x 512 threads. Each block owns a DISTINCT W tile:
// rows = 4 gates x 32 jj (mt), K-slice kseg*128..+127  (64 KB -> W traffic
// is 16.8 MB/step total, no inter-block redundancy, no XCD assumption).
// Thread t: jj = t&31, bg = t>>5 (16 batch-groups of 8). acc[4][8].
// Per thread: 384 float4 loads, 4096 FMAs -> VALU-bound.
// Partial row layout matches R1: row = mt*128 + jj*4 + gate.
// ---------------------------------------------------------------------------
__global__ __launch_bounds__(512, 2)
void gemm_step(const float* __restrict__ W, const float* __restrict__ hin,
               float* __restrict__ part) {
  int mt = blockIdx.x;       // 0..31
  int kseg = blockIdx.y;     // 0..7
  int t = threadIdx.x;
  int jj = t & 31;
  int bg = t >> 5;           // 0..15
  int b0 = bg * 8;
  int j = mt * 32 + jj;

  const float* wp0 = W + ((size_t)(0 * HID + j)) * HID + kseg * 128;
  const float* wp1 = W + ((size_t)(1 * HID + j)) * HID + kseg * 128;
  const float* wp2 = W + ((size_t)(2 * HID + j)) * HID + kseg * 128;
  const float* wp3 = W + ((size_t)(3 * HID + j)) * HID + kseg * 128;
  const float* hp  = hin + (size_t)(kseg * 128) * BATCH + b0;

  float acc[4][8] = {};
  for (int kq = 0; kq < 32; kq++) {          // 4 k per iteration
    float4 w0 = *(const float4*)(wp0 + 4 * kq);
    float4 w1 = *(const float4*)(wp1 + 4 * kq);
    float4 w2 = *(const float4*)(wp2 + 4 * kq);
    float4 w3 = *(const float4*)(wp3 + 4 * kq);
    float wg[4][4] = {{w0.x, w0.y, w0.z, w0.w}, {w1.x, w1.y, w1.z, w1.w},
                      {w2.x, w2.y, w2.z, w2.w}, {w3.x, w3.y, w3.z, w3.w}};
#pragma unroll
    for (int e = 0; e < 4; e++) {
      const float* hk = hp + (size_t)(4 * kq + e) * BATCH;
      float4 h0 = *(const float4*)(hk);
      float4 h1 = *(const float4*)(hk + 4);
      float hb[8] = {h0.x, h0.y, h0.z, h0.w, h1.x, h1.y, h1.z, h1.w};
#pragma unroll
      for (int g = 0; g < 4; g++)
#pragma unroll
        for (int b = 0; b < 8; b++)
          acc[g][b] = fmaf(wg[g][e], hb[b], acc[g][b]);
    }
  }

  float* dst = part + ((size_t)kseg * G4 + mt * 128 + jj * 4) * BATCH + b0;
#pragma unroll
  for (int g = 0; g < 4; g++) {
    *(float4*)(dst + (size_t)g * BATCH) =
        make_float4(acc[g][0], acc[g][1], acc[g][2], acc[g][3]);
    *(float4*)(dst + (size_t)g * BATCH + 4) =
        make_float4(acc[g][4], acc[g][5], acc[g][6], acc[g][7]);
  }
}

// ---------------------------------------------------------------------------
// cell_update: reduce 8 K-partials + x_proj, apply LSTM cell (R1-proven)
// ---------------------------------------------------------------------------
__global__ void cell_update(const float* __restrict__ part, const float* __restrict__ xp,
                            int N, int tt, float* __restrict__ hT, float* __restrict__ cT) {
  int idx = blockIdx.x * blockDim.x + threadIdx.x;  // < HID*BATCH
  int b = idx & (BATCH - 1);
  int j = idx >> 7;
  int rowbase = (j >> 5) * 128 + (j & 31) * 4;
  float pre[4];
#pragma unroll
  for (int g = 0; g < 4; g++) {
    float s = xp[(size_t)(g * HID + j) * N + (size_t)tt * BATCH + b];
#pragma unroll
    for (int p = 0; p < 8; p++)
      s += part[((size_t)p * G4 + rowbase + g) * BATCH + b];
    pre[g] = s;
  }
  float ig = 1.f / (1.f + expf(-pre[0]));
  float fg = 1.f / (1.f + expf(-pre[1]));
  float gg = tanhf(pre[2]);
  float og = 1.f / (1.f + expf(-pre[3]));
  float cn = fg * cT[idx] + ig * gg;
  cT[idx] = cn;
  hT[idx] = og * tanhf(cn);
}

// ---------------------------------------------------------------------------
// decode + softmax over batch dim (axis 0)
// ---------------------------------------------------------------------------
__global__ void decode_softmax(const float* __restrict__ hT, const float* __restrict__ Wd,
                               const float* __restrict__ bd, float* __restrict__ out) {
  __shared__ float lg[NOUT][BATCH];
  __shared__ float mx[NOUT], sm[NOUT];
  int t = threadIdx.x;  // 512 threads
  int b = t >> 2, o = t & 3;
  float s = bd[o];
  for (int j = 0; j < HID; j++) s += hT[j * BATCH + b] * Wd[o * HID + j];
  lg[o][b] = s;
  __syncthreads();
  if (t < NOUT) {
    float m = -1e30f;
    for (int b2 = 0; b2 < BATCH; b2++) m = fmaxf(m, lg[t][b2]);
    float ss = 0.f;
    for (int b2 = 0; b2 < BATCH; b2++) ss += expf(lg[t][b2] - m);
    mx[t] = m; sm[t] = ss;
  }
  __syncthreads();
  out[b * NOUT + o] = expf(lg[o][b] - mx[o]) / sm[o];
}

// ---------------------------------------------------------------------------
extern "C" void kernel_launch(void* const* d_in, const int* in_sizes, int n_in,
                              void* d_out, int out_size, void* d_ws, size_t ws_size,
                              hipStream_t stream) {
  const float* inputs = (const float*)d_in[0];
  const float* h0     = (const float*)d_in[1];
  const float* c0     = (const float*)d_in[2];
  const float* W_ih   = (const float*)d_in[3];
  const float* W_hh   = (const float*)d_in[4];
  const float* b_ih   = (const float*)d_in[5];
  const float* b_hh   = (const float*)d_in[6];
  const float* W_dec  = (const float*)d_in[7];
  const float* b_dec  = (const float*)d_in[8];
  float* out = (float*)d_out;

  char* w = (char*)d_ws;
  float* hT = (float*)w;   w += (size_t)HID * BATCH * 4;
  float* cT = (float*)w;   w += (size_t)HID * BATCH * 4;
  float* part = (float*)w; w += (size_t)8 * G4 * BATCH * 4;
  size_t used = (size_t)(w - (char*)d_ws);

  // chunk size over timesteps, sized to fit ws (deterministic: ws_size const)
  size_t per_ct = ((size_t)INP * BATCH + (size_t)G4 * BATCH) * 4;  // Xt + XP per step
  int CT = 1;
  if (ws_size > used) {
    size_t avail = (ws_size - used) / per_ct;
    for (int c = SEQ; c >= 1; c >>= 1)
      if ((size_t)c <= avail) { CT = c; break; }
  }
  float* Xt = (float*)w;   w += (size_t)INP * BATCH * CT * 4;
  float* XP = (float*)w;
  int N = CT * BATCH;

  init_state<<<HID * BATCH / 256, 256, 0, stream>>>(h0, c0, hT, cT);

  for (int t0 = 0; t0 < SEQ; t0 += CT) {
    transpose_in<<<dim3(N / 32, INP / 32), 256, 0, stream>>>(
        inputs + (size_t)t0 * BATCH * INP, Xt, N);
    gemm_xproj<<<dim3(G4 / 128, N / 128), 256, 0, stream>>>(
        W_ih, Xt, b_ih, b_hh, XP, N);
    for (int tt = 0; tt < CT; tt++) {
      gemm_step<<<dim3(32, 8), 512, 0, stream>>>(W_hh, hT, part);
      cell_update<<<HID * BATCH / 256, 256, 0, stream>>>(part, XP, N, tt, hT, cT);
    }
  }

  decode_softmax<<<1, 512, 0, stream>>>(hT, W_dec, b_dec, out);
}

// Round 6
// 15319.519 us; speedup vs baseline: 2.2277x; 2.2277x over previous
//
#include <hip/hip_runtime.h>
#include <math.h>

#define SEQ   512
#define BATCH 128
#define INP   512
#define HID   1024
#define G4    4096   // 4*HID
#define NOUT  4

typedef short bf16x8 __attribute__((ext_vector_type(8)));
typedef float f32x4  __attribute__((ext_vector_type(4)));

__device__ __forceinline__ unsigned short f2bf(float x) {  // RNE fp32->bf16
  unsigned int u = __float_as_uint(x);
  unsigned int r = (u + 0x7FFFu + ((u >> 16) & 1u)) >> 16;
  return (unsigned short)r;
}
__device__ __forceinline__ float bf2f(unsigned short h) {
  return __uint_as_float(((unsigned int)h) << 16);
}

// ---------------------------------------------------------------------------
// prepack W_hh [4096][1024] fp32 into fragment-linear bf16 hi/lo:
// out index ((bk*32 + kstep)*64 + L)*8 + i  holds W[row][k] with
//   m = L&15, q = L>>4, g = m&3, jj = m>>2, row = g*HID + bk*4 + jj,
//   k = kstep*32 + q*8 + i.
// A-frag for wave then loads 16B at (bk,kstep) base + 16*L — fully linear.
// ---------------------------------------------------------------------------
__global__ void prepack_w(const float* __restrict__ W,
                          unsigned short* __restrict__ Whi,
                          unsigned short* __restrict__ Wlo) {
  int T = blockIdx.x * blockDim.x + threadIdx.x;   // < 256*32*64
  int L = T & 63;
  int kstep = (T >> 6) & 31;
  int bk = T >> 11;
  int m = L & 15, q = L >> 4;
  int row = (m & 3) * HID + bk * 4 + (m >> 2);
  int k = kstep * 32 + q * 8;
  const float* src = W + (size_t)row * HID + k;
  unsigned short hi[8], lo[8];
#pragma unroll
  for (int i = 0; i < 8; i++) {
    float x = src[i];
    unsigned short h = f2bf(x);
    hi[i] = h;
    lo[i] = f2bf(x - bf2f(h));
  }
  size_t o = (size_t)T * 8;
#pragma unroll
  for (int i = 0; i < 8; i++) { Whi[o + i] = hi[i]; Wlo[o + i] = lo[i]; }
}

// ---------------------------------------------------------------------------
// init: h0 [B][H] fp32 -> h_hi/h_lo [B][H] bf16 (same layout);
//       c0 [B][H] -> cT [H][B] fp32 (transposed).
// ---------------------------------------------------------------------------
__global__ void init_state(const float* __restrict__ h0, const float* __restrict__ c0,
                           unsigned short* __restrict__ hhi, unsigned short* __restrict__ hlo,
                           float* __restrict__ cT) {
  int idx = blockIdx.x * blockDim.x + threadIdx.x;  // < BATCH*HID
  int b = idx >> 10;          // h layout [b][j]
  int j = idx & (HID - 1);
  float x = h0[idx];
  unsigned short h = f2bf(x);
  hhi[idx] = h;
  hlo[idx] = f2bf(x - bf2f(h));
  cT[j * BATCH + b] = c0[idx];
}

// ---------------------------------------------------------------------------
// transpose a chunk of inputs: in [nrows][INP] -> xt [INP][nrows]
// ---------------------------------------------------------------------------
__global__ void transpose_in(const float* __restrict__ in, float* __restrict__ xt,
                             int nrows) {
  __shared__ float s[32][33];
  int tx = threadIdx.x & 31, ty = threadIdx.x >> 5;  // ty < 8
  int n0 = blockIdx.x * 32, i0 = blockIdx.y * 32;
#pragma unroll
  for (int r = 0; r < 4; r++) {
    int n = n0 + ty + 8 * r;
    s[ty + 8 * r][tx] = in[(size_t)n * INP + i0 + tx];
  }
  __syncthreads();
#pragma unroll
  for (int r = 0; r < 4; r++) {
    int i = i0 + ty + 8 * r;
    xt[(size_t)i * nrows + n0 + tx] = s[tx][ty + 8 * r];
  }
}

// ---------------------------------------------------------------------------
// gemm_xproj: C[4096][N] = W_ih[4096][512] @ Xt[512][N] + (b_ih + b_hh)
// (proven round-1 kernel, unchanged)
// ---------------------------------------------------------------------------
__global__ __launch_bounds__(256, 3)
void gemm_xproj(const float* __restrict__ A, const float* __restrict__ Bm,
                const float* __restrict__ b_ih, const float* __restrict__ b_hh,
                float* __restrict__ C, int N) {
  __shared__ float As[32][128];
  __shared__ float Bs[32][128];
  int t = threadIdx.x;
  int g0 = blockIdx.x * 128;
  int n0 = blockIdx.y * 128;
  int mg = (t >> 4) * 8, nn = (t & 15) * 8;
  float acc[8][8] = {};
  for (int k0 = 0; k0 < INP; k0 += 32) {
#pragma unroll
    for (int r = 0; r < 4; r++) {
      int idx = t + 256 * r;
      int g = idx >> 3, i4 = idx & 7;
      float4 v = *(const float4*)&A[(size_t)(g0 + g) * INP + k0 + 4 * i4];
      As[4 * i4 + 0][g] = v.x; As[4 * i4 + 1][g] = v.y;
      As[4 * i4 + 2][g] = v.z; As[4 * i4 + 3][g] = v.w;
    }
#pragma unroll
    for (int r = 0; r < 4; r++) {
      int idx = t + 256 * r;
      int kk = idx >> 5, n4 = idx & 31;
      *(float4*)&Bs[kk][4 * n4] = *(const float4*)&Bm[(size_t)(k0 + kk) * N + n0 + 4 * n4];
    }
    __syncthreads();
#pragma unroll 4
    for (int kk = 0; kk < 32; kk++) {
      float4 a0 = *(const float4*)&As[kk][mg];
      float4 a1 = *(const float4*)&As[kk][mg + 4];
      float4 bb0 = *(const float4*)&Bs[kk][nn];
      float4 bb1 = *(const float4*)&Bs[kk][nn + 4];
      float av[8] = {a0.x, a0.y, a0.z, a0.w, a1.x, a1.y, a1.z, a1.w};
      float bv[8] = {bb0.x, bb0.y, bb0.z, bb0.w, bb1.x, bb1.y, bb1.z, bb1.w};
#pragma unroll
      for (int i2 = 0; i2 < 8; i2++)
#pragma unroll
        for (int j2 = 0; j2 < 8; j2++)
          acc[i2][j2] = fmaf(av[i2], bv[j2], acc[i2][j2]);
    }
    __syncthreads();
  }
#pragma unroll
  for (int i2 = 0; i2 < 8; i2++) {
    int g = g0 + mg + i2;
    float bias = b_ih[g] + b_hh[g];
#pragma unroll
    for (int j2 = 0; j2 < 8; j2++) {
      C[(size_t)g * N + n0 + nn + j2] = acc[i2][j2] + bias;
    }
  }
}

// ---------------------------------------------------------------------------
// lstm_step: ONE dispatch per timestep. MFMA hi/lo-bf16, fused cell update.
// 256 blocks x 512 thr (8 waves). Block bk owns j = 4bk..4bk+3 (16 W rows),
// wave w owns batch tile b = 16w..16w+15. K = 1024 (32 MFMA k-steps x 3).
// A-frag: fragment-linear prepacked W (16B/lane, contiguous per wave).
// B-frag: h [B][H] bf16 — lane n=L&15 -> b, k contiguous (16B, one 64B
// line per b). C/D: col=lane&15 (b), row=(L>>4)*4+reg -> lane holds the 4
// gate preacts of (j = 4bk + (L>>4), b = 16w + (L&15)) in its 4 acc regs.
// Cell update entirely per-lane; h out ping-pong (kernel-boundary coherence).
// ---------------------------------------------------------------------------
__global__ __launch_bounds__(512)
void lstm_step(const unsigned short* __restrict__ Whi,
               const unsigned short* __restrict__ Wlo,
               const float* __restrict__ xp, int N,
               const unsigned short* __restrict__ hin_hi,
               const unsigned short* __restrict__ hin_lo,
               unsigned short* __restrict__ hout_hi,
               unsigned short* __restrict__ hout_lo,
               float* __restrict__ cT) {
  int bk = blockIdx.x;            // 0..255
  int t = threadIdx.x;
  int w = t >> 6;                 // wave -> batch tile
  int L = t & 63;
  int n = L & 15, q = L >> 4;

  const unsigned short* Ah = Whi + ((size_t)bk * 32) * 512 + (size_t)L * 8;
  const unsigned short* Al = Wlo + ((size_t)bk * 32) * 512 + (size_t)L * 8;
  const unsigned short* Bh = hin_hi + (size_t)(w * 16 + n) * HID + q * 8;
  const unsigned short* Bl = hin_lo + (size_t)(w * 16 + n) * HID + q * 8;

  f32x4 acc = {0.f, 0.f, 0.f, 0.f};
#pragma unroll 4
  for (int ks = 0; ks < 32; ks++) {
    bf16x8 ah = *(const bf16x8*)(Ah + ks * 512);
    bf16x8 al = *(const bf16x8*)(Al + ks * 512);
    bf16x8 bh = *(const bf16x8*)(Bh + ks * 32);
    bf16x8 bl = *(const bf16x8*)(Bl + ks * 32);
    acc = __builtin_amdgcn_mfma_f32_16x16x32_bf16(ah, bh, acc, 0, 0, 0);
    acc = __builtin_amdgcn_mfma_f32_16x16x32_bf16(ah, bl, acc, 0, 0, 0);
    acc = __builtin_amdgcn_mfma_f32_16x16x32_bf16(al, bh, acc, 0, 0, 0);
  }

  int j = bk * 4 + q;
  int b = w * 16 + n;
  float pre[4];
#pragma unroll
  for (int g = 0; g < 4; g++)
    pre[g] = acc[g] + xp[(size_t)(g * HID + j) * N + b];

  float ig = 1.f / (1.f + expf(-pre[0]));
  float fg = 1.f / (1.f + expf(-pre[1]));
  float gg = tanhf(pre[2]);
  float og = 1.f / (1.f + expf(-pre[3]));
  int ci = j * BATCH + b;
  float cn = fg * cT[ci] + ig * gg;
  cT[ci] = cn;
  float hn = og * tanhf(cn);

  unsigned short hh = f2bf(hn);
  hout_hi[(size_t)b * HID + j] = hh;
  hout_lo[(size_t)b * HID + j] = f2bf(hn - bf2f(hh));
}

// ---------------------------------------------------------------------------
// decode + softmax over batch dim (axis 0); h from hi+lo bf16 [B][H]
// ---------------------------------------------------------------------------
__global__ void decode_softmax(const unsigned short* __restrict__ hhi,
                               const unsigned short* __restrict__ hlo,
                               const float* __restrict__ Wd,
                               const float* __restrict__ bd, float* __restrict__ out) {
  __shared__ float lg[NOUT][BATCH];
  __shared__ float mx[NOUT], sm[NOUT];
  int t = threadIdx.x;  // 512 threads
  int b = t >> 2, o = t & 3;
  float s = bd[o];
  for (int j = 0; j < HID; j++) {
    float hv = bf2f(hhi[(size_t)b * HID + j]) + bf2f(hlo[(size_t)b * HID + j]);
    s += hv * Wd[o * HID + j];
  }
  lg[o][b] = s;
  __syncthreads();
  if (t < NOUT) {
    float m = -1e30f;
    for (int b2 = 0; b2 < BATCH; b2++) m = fmaxf(m, lg[t][b2]);
    float ss = 0.f;
    for (int b2 = 0; b2 < BATCH; b2++) ss += expf(lg[t][b2] - m);
    mx[t] = m; sm[t] = ss;
  }
  __syncthreads();
  out[b * NOUT + o] = expf(lg[o][b] - mx[o]) / sm[o];
}

// ---------------------------------------------------------------------------
extern "C" void kernel_launch(void* const* d_in, const int* in_sizes, int n_in,
                              void* d_out, int out_size, void* d_ws, size_t ws_size,
                              hipStream_t stream) {
  const float* inputs = (const float*)d_in[0];
  const float* h0     = (const float*)d_in[1];
  const float* c0     = (const float*)d_in[2];
  const float* W_ih   = (const float*)d_in[3];
  const float* W_hh   = (const float*)d_in[4];
  const float* b_ih   = (const float*)d_in[5];
  const float* b_hh   = (const float*)d_in[6];
  const float* W_dec  = (const float*)d_in[7];
  const float* b_dec  = (const float*)d_in[8];
  float* out = (float*)d_out;

  char* w = (char*)d_ws;
  unsigned short* Whi = (unsigned short*)w;  w += (size_t)G4 * HID * 2;
  unsigned short* Wlo = (unsigned short*)w;  w += (size_t)G4 * HID * 2;
  unsigned short* hhi[2], *hlo[2];
  hhi[0] = (unsigned short*)w;  w += (size_t)BATCH * HID * 2;
  hhi[1] = (unsigned short*)w;  w += (size_t)BATCH * HID * 2;
  hlo[0] = (unsigned short*)w;  w += (size_t)BATCH * HID * 2;
  hlo[1] = (unsigned short*)w;  w += (size_t)BATCH * HID * 2;
  float* cT = (float*)w;        w += (size_t)HID * BATCH * 4;
  size_t used = (size_t)(w - (char*)d_ws);

  // chunk size over timesteps, sized to fit ws (deterministic: ws_size const)
  size_t per_ct = ((size_t)INP * BATCH + (size_t)G4 * BATCH) * 4;  // Xt + XP per step
  int CT = 1;
  if (ws_size > used) {
    size_t avail = (ws_size - used) / per_ct;
    for (int c = SEQ; c >= 1; c >>= 1)
      if ((size_t)c <= avail) { CT = c; break; }
  }
  float* Xt = (float*)w;  w += (size_t)INP * BATCH * CT * 4;
  float* XP = (float*)w;
  int N = CT * BATCH;

  prepack_w<<<(256 * 32 * 64) / 256, 256, 0, stream>>>(W_hh, Whi, Wlo);
  init_state<<<BATCH * HID / 256, 256, 0, stream>>>(h0, c0, hhi[0], hlo[0], cT);

  for (int t0 = 0; t0 < SEQ; t0 += CT) {
    transpose_in<<<dim3(N / 32, INP / 32), 256, 0, stream>>>(
        inputs + (size_t)t0 * BATCH * INP, Xt, N);
    gemm_xproj<<<dim3(G4 / 128, N / 128), 256, 0, stream>>>(
        W_ih, Xt, b_ih, b_hh, XP, N);
    for (int tt = 0; tt < CT; tt++) {
      int gs = t0 + tt;                            // global step index
      int src = gs & 1, dst = 1 - src;
      const float* xpc = XP + (size_t)tt * BATCH;  // column block for this step
      lstm_step<<<256, 512, 0, stream>>>(
          Whi, Wlo, xpc, N, hhi[src], hlo[src], hhi[dst], hlo[dst], cT);
    }
  }

  // SEQ even -> final h in buffer 0
  decode_softmax<<<1, 512, 0, stream>>>(hhi[0], hlo[0], W_dec, b_dec, out);
}

// Round 7
// 13063.182 us; speedup vs baseline: 2.6125x; 1.1727x over previous
//
#include <hip/hip_runtime.h>
#include <math.h>

#define SEQ   512
#define BATCH 128
#define INP   512
#define HID   1024
#define G4    4096   // 4*HID
#define NOUT  4

typedef short bf16x8 __attribute__((ext_vector_type(8)));
typedef float f32x4  __attribute__((ext_vector_type(4)));

__device__ __forceinline__ unsigned short f2bf(float x) {  // RNE fp32->bf16
  unsigned int u = __float_as_uint(x);
  unsigned int r = (u + 0x7FFFu + ((u >> 16) & 1u)) >> 16;
  return (unsigned short)r;
}
__device__ __forceinline__ float bf2f(unsigned short h) {
  return __uint_as_float(((unsigned int)h) << 16);
}

// ---------------------------------------------------------------------------
// prepack W_hh [4096][1024] fp32 into fragment-linear bf16 hi/lo:
// out index ((bk*32 + kstep)*64 + L)*8 + i  holds W[row][k] with
//   m = L&15, q = L>>4, g = m&3, jj = m>>2, row = g*HID + bk*4 + jj,
//   k = kstep*32 + q*8 + i.
// Block bk's slab is contiguous (16384 shorts = 32 KB per buffer).
// ---------------------------------------------------------------------------
__global__ void prepack_w(const float* __restrict__ W,
                          unsigned short* __restrict__ Whi,
                          unsigned short* __restrict__ Wlo) {
  int T = blockIdx.x * blockDim.x + threadIdx.x;   // < 256*32*64
  int L = T & 63;
  int kstep = (T >> 6) & 31;
  int bk = T >> 11;
  int m = L & 15, q = L >> 4;
  int row = (m & 3) * HID + bk * 4 + (m >> 2);
  int k = kstep * 32 + q * 8;
  const float* src = W + (size_t)row * HID + k;
  unsigned short hi[8], lo[8];
#pragma unroll
  for (int i = 0; i < 8; i++) {
    float x = src[i];
    unsigned short h = f2bf(x);
    hi[i] = h;
    lo[i] = f2bf(x - bf2f(h));
  }
  size_t o = (size_t)T * 8;
#pragma unroll
  for (int i = 0; i < 8; i++) { Whi[o + i] = hi[i]; Wlo[o + i] = lo[i]; }
}

// ---------------------------------------------------------------------------
// init: h0 [B][H] fp32 -> h_hi/h_lo [B][H] bf16 (same layout);
//       c0 [B][H] -> cT [H][B] fp32 (transposed).
// ---------------------------------------------------------------------------
__global__ void init_state(const float* __restrict__ h0, const float* __restrict__ c0,
                           unsigned short* __restrict__ hhi, unsigned short* __restrict__ hlo,
                           float* __restrict__ cT) {
  int idx = blockIdx.x * blockDim.x + threadIdx.x;  // < BATCH*HID
  int b = idx >> 10;          // h layout [b][j]
  int j = idx & (HID - 1);
  float x = h0[idx];
  unsigned short h = f2bf(x);
  hhi[idx] = h;
  hlo[idx] = f2bf(x - bf2f(h));
  cT[j * BATCH + b] = c0[idx];
}

// ---------------------------------------------------------------------------
// transpose a chunk of inputs: in [nrows][INP] -> xt [INP][nrows]
// ---------------------------------------------------------------------------
__global__ void transpose_in(const float* __restrict__ in, float* __restrict__ xt,
                             int nrows) {
  __shared__ float s[32][33];
  int tx = threadIdx.x & 31, ty = threadIdx.x >> 5;  // ty < 8
  int n0 = blockIdx.x * 32, i0 = blockIdx.y * 32;
#pragma unroll
  for (int r = 0; r < 4; r++) {
    int n = n0 + ty + 8 * r;
    s[ty + 8 * r][tx] = in[(size_t)n * INP + i0 + tx];
  }
  __syncthreads();
#pragma unroll
  for (int r = 0; r < 4; r++) {
    int i = i0 + ty + 8 * r;
    xt[(size_t)i * nrows + n0 + tx] = s[tx][ty + 8 * r];
  }
}

// ---------------------------------------------------------------------------
// gemm_xproj: C[4096][N] = W_ih[4096][512] @ Xt[512][N] + (b_ih + b_hh)
// (proven round-1 kernel, unchanged)
// ---------------------------------------------------------------------------
__global__ __launch_bounds__(256, 3)
void gemm_xproj(const float* __restrict__ A, const float* __restrict__ Bm,
                const float* __restrict__ b_ih, const float* __restrict__ b_hh,
                float* __restrict__ C, int N) {
  __shared__ float As[32][128];
  __shared__ float Bs[32][128];
  int t = threadIdx.x;
  int g0 = blockIdx.x * 128;
  int n0 = blockIdx.y * 128;
  int mg = (t >> 4) * 8, nn = (t & 15) * 8;
  float acc[8][8] = {};
  for (int k0 = 0; k0 < INP; k0 += 32) {
#pragma unroll
    for (int r = 0; r < 4; r++) {
      int idx = t + 256 * r;
      int g = idx >> 3, i4 = idx & 7;
      float4 v = *(const float4*)&A[(size_t)(g0 + g) * INP + k0 + 4 * i4];
      As[4 * i4 + 0][g] = v.x; As[4 * i4 + 1][g] = v.y;
      As[4 * i4 + 2][g] = v.z; As[4 * i4 + 3][g] = v.w;
    }
#pragma unroll
    for (int r = 0; r < 4; r++) {
      int idx = t + 256 * r;
      int kk = idx >> 5, n4 = idx & 31;
      *(float4*)&Bs[kk][4 * n4] = *(const float4*)&Bm[(size_t)(k0 + kk) * N + n0 + 4 * n4];
    }
    __syncthreads();
#pragma unroll 4
    for (int kk = 0; kk < 32; kk++) {
      float4 a0 = *(const float4*)&As[kk][mg];
      float4 a1 = *(const float4*)&As[kk][mg + 4];
      float4 bb0 = *(const float4*)&Bs[kk][nn];
      float4 bb1 = *(const float4*)&Bs[kk][nn + 4];
      float av[8] = {a0.x, a0.y, a0.z, a0.w, a1.x, a1.y, a1.z, a1.w};
      float bv[8] = {bb0.x, bb0.y, bb0.z, bb0.w, bb1.x, bb1.y, bb1.z, bb1.w};
#pragma unroll
      for (int i2 = 0; i2 < 8; i2++)
#pragma unroll
        for (int j2 = 0; j2 < 8; j2++)
          acc[i2][j2] = fmaf(av[i2], bv[j2], acc[i2][j2]);
    }
    __syncthreads();
  }
#pragma unroll
  for (int i2 = 0; i2 < 8; i2++) {
    int g = g0 + mg + i2;
    float bias = b_ih[g] + b_hh[g];
#pragma unroll
    for (int j2 = 0; j2 < 8; j2++) {
      C[(size_t)g * N + n0 + nn + j2] = acc[i2][j2] + bias;
    }
  }
}

// ---------------------------------------------------------------------------
// lstm_step: ONE dispatch per timestep. MFMA hi/lo-bf16, fused cell update.
// 256 blocks x 512 thr (8 waves). Block bk owns j = 4bk..4bk+3 (16 W rows),
// wave w owns batch tile b = 16w..16w+15. K = 1024 (32 MFMA k-steps x 3).
// NEW (R7): W tile (64 KB hi+lo) is LDS-staged once per step (cooperative
// float4 copy) -> kills the 8x cross-wave A-frag redundancy that made R6
// L2-ingest-bound (1 MB -> 576 KB per block per step). A-frags now
// conflict-free ds_read_b128 (lane-consecutive 16 B). xp/cT prefetched
// before the MFMA loop so epilogue load latency overlaps compute.
// C/D: col=lane&15 (b), row=(L>>4)*4+reg -> lane holds all 4 gate preacts
// of (j = 4bk + (L>>4), b = 16w + (L&15)). Cell update per-lane; h out
// ping-pong (kernel-boundary coherence).
// ---------------------------------------------------------------------------
__global__ __launch_bounds__(512)
void lstm_step(const unsigned short* __restrict__ Whi,
               const unsigned short* __restrict__ Wlo,
               const float* __restrict__ xp, int N,
               const unsigned short* __restrict__ hin_hi,
               const unsigned short* __restrict__ hin_lo,
               unsigned short* __restrict__ hout_hi,
               unsigned short* __restrict__ hout_lo,
               float* __restrict__ cT) {
  __shared__ bf16x8 Wlds[4096];        // [0..2047]=hi, [2048..4095]=lo (64 KB)

  int bk = blockIdx.x;            // 0..255
  int t = threadIdx.x;
  int w = t >> 6;                 // wave -> batch tile
  int L = t & 63;
  int n = L & 15, q = L >> 4;

  // ---- stage W tile into LDS (fragment-linear, contiguous slab) ----
  {
    float4* ldsf = (float4*)Wlds;
    const float4* s1 = (const float4*)(Whi + (size_t)bk * 16384);
    const float4* s2 = (const float4*)(Wlo + (size_t)bk * 16384);
#pragma unroll
    for (int i = 0; i < 4; i++) ldsf[t + 512 * i] = s1[t + 512 * i];
#pragma unroll
    for (int i = 0; i < 4; i++) ldsf[2048 + t + 512 * i] = s2[t + 512 * i];
  }

  // ---- prefetch epilogue operands (independent of MFMA loop) ----
  int j = bk * 4 + q;
  int b = w * 16 + n;
  int ci = j * BATCH + b;
  float xpv[4];
#pragma unroll
  for (int g = 0; g < 4; g++)
    xpv[g] = xp[(size_t)(g * HID + j) * N + b];
  float cold = cT[ci];

  __syncthreads();

  const unsigned short* Bh = hin_hi + (size_t)b * HID + q * 8;
  const unsigned short* Bl = hin_lo + (size_t)b * HID + q * 8;

  f32x4 acc = {0.f, 0.f, 0.f, 0.f};
#pragma unroll 4
  for (int ks = 0; ks < 32; ks++) {
    bf16x8 ah = Wlds[ks * 64 + L];
    bf16x8 al = Wlds[2048 + ks * 64 + L];
    bf16x8 bh = *(const bf16x8*)(Bh + ks * 32);
    bf16x8 bl = *(const bf16x8*)(Bl + ks * 32);
    acc = __builtin_amdgcn_mfma_f32_16x16x32_bf16(ah, bh, acc, 0, 0, 0);
    acc = __builtin_amdgcn_mfma_f32_16x16x32_bf16(ah, bl, acc, 0, 0, 0);
    acc = __builtin_amdgcn_mfma_f32_16x16x32_bf16(al, bh, acc, 0, 0, 0);
  }

  float pre[4];
#pragma unroll
  for (int g = 0; g < 4; g++)
    pre[g] = acc[g] + xpv[g];

  float ig = 1.f / (1.f + expf(-pre[0]));
  float fg = 1.f / (1.f + expf(-pre[1]));
  float gg = tanhf(pre[2]);
  float og = 1.f / (1.f + expf(-pre[3]));
  float cn = fg * cold + ig * gg;
  cT[ci] = cn;
  float hn = og * tanhf(cn);

  unsigned short hh = f2bf(hn);
  hout_hi[(size_t)b * HID + j] = hh;
  hout_lo[(size_t)b * HID + j] = f2bf(hn - bf2f(hh));
}

// ---------------------------------------------------------------------------
// decode + softmax over batch dim (axis 0); h from hi+lo bf16 [B][H]
// ---------------------------------------------------------------------------
__global__ void decode_softmax(const unsigned short* __restrict__ hhi,
                               const unsigned short* __restrict__ hlo,
                               const float* __restrict__ Wd,
                               const float* __restrict__ bd, float* __restrict__ out) {
  __shared__ float lg[NOUT][BATCH];
  __shared__ float mx[NOUT], sm[NOUT];
  int t = threadIdx.x;  // 512 threads
  int b = t >> 2, o = t & 3;
  float s = bd[o];
  for (int j = 0; j < HID; j++) {
    float hv = bf2f(hhi[(size_t)b * HID + j]) + bf2f(hlo[(size_t)b * HID + j]);
    s += hv * Wd[o * HID + j];
  }
  lg[o][b] = s;
  __syncthreads();
  if (t < NOUT) {
    float m = -1e30f;
    for (int b2 = 0; b2 < BATCH; b2++) m = fmaxf(m, lg[t][b2]);
    float ss = 0.f;
    for (int b2 = 0; b2 < BATCH; b2++) ss += expf(lg[t][b2] - m);
    mx[t] = m; sm[t] = ss;
  }
  __syncthreads();
  out[b * NOUT + o] = expf(lg[o][b] - mx[o]) / sm[o];
}

// ---------------------------------------------------------------------------
extern "C" void kernel_launch(void* const* d_in, const int* in_sizes, int n_in,
                              void* d_out, int out_size, void* d_ws, size_t ws_size,
                              hipStream_t stream) {
  const float* inputs = (const float*)d_in[0];
  const float* h0     = (const float*)d_in[1];
  const float* c0     = (const float*)d_in[2];
  const float* W_ih   = (const float*)d_in[3];
  const float* W_hh   = (const float*)d_in[4];
  const float* b_ih   = (const float*)d_in[5];
  const float* b_hh   = (const float*)d_in[6];
  const float* W_dec  = (const float*)d_in[7];
  const float* b_dec  = (const float*)d_in[8];
  float* out = (float*)d_out;

  char* w = (char*)d_ws;
  unsigned short* Whi = (unsigned short*)w;  w += (size_t)G4 * HID * 2;
  unsigned short* Wlo = (unsigned short*)w;  w += (size_t)G4 * HID * 2;
  unsigned short* hhi[2], *hlo[2];
  hhi[0] = (unsigned short*)w;  w += (size_t)BATCH * HID * 2;
  hhi[1] = (unsigned short*)w;  w += (size_t)BATCH * HID * 2;
  hlo[0] = (unsigned short*)w;  w += (size_t)BATCH * HID * 2;
  hlo[1] = (unsigned short*)w;  w += (size_t)BATCH * HID * 2;
  float* cT = (float*)w;        w += (size_t)HID * BATCH * 4;
  size_t used = (size_t)(w - (char*)d_ws);

  // chunk size over timesteps, sized to fit ws (deterministic: ws_size const)
  size_t per_ct = ((size_t)INP * BATCH + (size_t)G4 * BATCH) * 4;  // Xt + XP per step
  int CT = 1;
  if (ws_size > used) {
    size_t avail = (ws_size - used) / per_ct;
    for (int c = SEQ; c >= 1; c >>= 1)
      if ((size_t)c <= avail) { CT = c; break; }
  }
  float* Xt = (float*)w;  w += (size_t)INP * BATCH * CT * 4;
  float* XP = (float*)w;
  int N = CT * BATCH;

  prepack_w<<<(256 * 32 * 64) / 256, 256, 0, stream>>>(W_hh, Whi, Wlo);
  init_state<<<BATCH * HID / 256, 256, 0, stream>>>(h0, c0, hhi[0], hlo[0], cT);

  for (int t0 = 0; t0 < SEQ; t0 += CT) {
    transpose_in<<<dim3(N / 32, INP / 32), 256, 0, stream>>>(
        inputs + (size_t)t0 * BATCH * INP, Xt, N);
    gemm_xproj<<<dim3(G4 / 128, N / 128), 256, 0, stream>>>(
        W_ih, Xt, b_ih, b_hh, XP, N);
    for (int tt = 0; tt < CT; tt++) {
      int gs = t0 + tt;                            // global step index
      int src = gs & 1, dst = 1 - src;
      const float* xpc = XP + (size_t)tt * BATCH;  // column block for this step
      lstm_step<<<256, 512, 0, stream>>>(
          Whi, Wlo, xpc, N, hhi[src], hlo[src], hhi[dst], hlo[dst], cT);
    }
  }

  // SEQ even -> final h in buffer 0
  decode_softmax<<<1, 512, 0, stream>>>(hhi[0], hlo[0], W_dec, b_dec, out);
}